// Round 20
// baseline (146.616 us; speedup 1.0000x reference)
//
#include <hip/hip_runtime.h>
#include <cstdint>

#define E_EDGES 400000
#define N_NODES 25000
#define NU      12500          // units of 32 edges (2 MFMA groups of 16)
#define NPACK   18432          // ushorts: 17 K-tiles (17408) + 2 W1^T A-frags (1024)
#define HB2     196            // histogram blocks (2048 edges each, 512 thr)
#define EBLK    782            // edge-compute blocks (512 thr = 8 waves)
#define NWAVES  (EBLK*8)       // 6256 waves; each does <=2 units (unrolled)

typedef float  f32x4  __attribute__((ext_vector_type(4)));
typedef __bf16 bf16x8 __attribute__((ext_vector_type(8)));

static __device__ __forceinline__ ushort f2bf(float f) {
    union { __bf16 b; ushort u; } c; c.b = (__bf16)f; return c.u;
}

// ---------------------------------------------------------------------------
// K_pre: zero agg+cnt8 (grid-stride) AND pack W2(+b2)/W1^T frags. One dispatch.
// kap(kg,j) = j<4 ? 4kg+j : 16+4kg+(j-4)   (matches h-MFMA C layout)
// ---------------------------------------------------------------------------
__global__ void __launch_bounds__(256) k_pre(const float* __restrict__ W2,
                                             const float* __restrict__ b2,
                                             const float* __restrict__ W1,
                                             ushort* __restrict__ packed,
                                             uint* __restrict__ zbase) {
    const int t = blockIdx.x * 256 + threadIdx.x;
    // zero 1,000,000 uints: agg (800,000) + cnt8 (200,000)
    for (int i = t; i < 1000000; i += 782 * 256) zbase[i] = 0u;
    if (t >= NPACK) return;
    float v = 0.0f;
    if (t < 17408) {
        int j  = t & 7;
        int ln = (t >> 3) & 15;
        int kg = (t >> 7) & 3;
        int nt = (t >> 9) & 1;
        int kt = t >> 10;
        int kap = (j < 4) ? (kg * 4 + j) : (16 + kg * 4 + (j - 4));
        if (kt < 16)       v = W2[kap * 512 + kt * 32 + nt * 16 + ln];
        else if (kap < 16) v = b2[kap * 32 + nt * 16 + ln];
    } else {
        int idx  = t - 17408;
        int half = idx >> 9;
        int lane = (idx >> 3) & 63;
        int j    = idx & 7;
        int kg = lane >> 4, ln = lane & 15;
        if (kg == 0) v = W1[j * 32 + half * 16 + ln];  // A[m=ln(+16*half)][k=j]
    }
    packed[t] = f2bf(v);
}

// ---------------------------------------------------------------------------
// K_edge: 512-thread blocks (8 waves) -> 4 blocks/CU x 8 = 32 waves/CU
// (2x the TLP of every prior round; requires VGPR <= 64, forced by
// __launch_bounds__(512,8); d4 de-prefetched to free 8 loop-carried regs).
// Blocks < HB2: 8-way-spread dst histogram. Blocks >= HB2: edge body.
// ---------------------------------------------------------------------------
__global__ void __launch_bounds__(512, 8) k_edge(const float* __restrict__ ea,
                                                 const float* __restrict__ x,
                                                 const int* __restrict__ ei,
                                                 const ushort* __restrict__ packed,
                                                 const float* __restrict__ b1,
                                                 float* __restrict__ agg,
                                                 uint* __restrict__ cnt8) {
    if (blockIdx.x < HB2) {
        const int base = blockIdx.x * 2048 + threadIdx.x * 4;
        if (base < E_EDGES) {
            const int4 dv = *(const int4*)(ei + E_EDGES + base);
            atomicAdd(&cnt8[dv.x * 8 + ((base + 0) & 7)], 1u);
            atomicAdd(&cnt8[dv.y * 8 + ((base + 1) & 7)], 1u);
            atomicAdd(&cnt8[dv.z * 8 + ((base + 2) & 7)], 1u);
            atomicAdd(&cnt8[dv.w * 8 + ((base + 3) & 7)], 1u);
        }
        return;
    }

    __shared__ alignas(16) ushort w2l[NPACK];
    __shared__ float b1l[32];
    {
        const uint4* s = (const uint4*)packed;
        uint4* d = (uint4*)w2l;
        for (int i = threadIdx.x; i < NPACK / 8; i += 512) d[i] = s[i];
        if (threadIdx.x < 32) b1l[threadIdx.x] = b1[threadIdx.x];
    }
    __syncthreads();

    const int lane = threadIdx.x & 63;
    const int ln = lane & 15;
    const int kg = lane >> 4;
    const int wid = (blockIdx.x - HB2) * 8 + (threadIdx.x >> 6);

    // loop-invariant A-frags for the h-MFMA (W1^T)
    const bf16x8 aw0 = *(const bf16x8*)(&w2l[17408 + lane * 8]);
    const bf16x8 aw1 = *(const bf16x8*)(&w2l[17408 + 512 + lane * 8]);
    const f32x4 z4 = {0.f, 0.f, 0.f, 0.f};
    const __bf16 zb = (__bf16)0.0f;

    int u = wid;                    // wid < 6256 <= NU always valid
    // ---- prologue: src indices + ea for unit u (dsts loaded in-body)
    int s0 = ei[u * 32 + ln];
    int s1 = ei[u * 32 + 16 + ln];
    const f32x4* ep0 = (const f32x4*)(ea + (size_t)(u * 32 + ln) * 8);
    f32x4 ea00 = ep0[0], ea01 = ep0[1];
    const f32x4* ep1 = (const f32x4*)(ea + (size_t)(u * 32 + 16 + ln) * 8);
    f32x4 ea10 = ep1[0], ea11 = ep1[1];

#pragma unroll
    for (int it = 0; it < 2; ++it) {
        const int un = u + NWAVES;
        const bool pf = (it == 0) && (un < NU);

        // ---- current unit's dst indices (needed only at scatter — whole
        //      MFMA block covers the latency; not loop-carried)
        const int4 d0 = *(const int4*)(ei + E_EDGES + u * 32 + kg * 4);
        const int4 d1 = *(const int4*)(ei + E_EDGES + u * 32 + 16 + kg * 4);

        // ---- x gathers for current unit (s0/s1 already in flight)
        const f32x4* xp0 = (const f32x4*)(x + (size_t)s0 * 16);
        const f32x4 xa0 = xp0[0], xa1 = xp0[1], xa2 = xp0[2], xa3 = xp0[3];
        const f32x4* xp1 = (const f32x4*)(x + (size_t)s1 * 16);
        const f32x4 xb0 = xp1[0], xb1 = xp1[1], xb2 = xp1[2], xb3 = xp1[3];

        // ---- prefetch next unit's src idx + ea (hidden under MFMAs)
        int ns0 = 0, ns1 = 0;
        f32x4 nea00 = z4, nea01 = z4, nea10 = z4, nea11 = z4;
        if (pf) {
            ns0 = ei[un * 32 + ln];
            ns1 = ei[un * 32 + 16 + ln];
            const f32x4* np0 = (const f32x4*)(ea + (size_t)(un * 32 + ln) * 8);
            nea00 = np0[0]; nea01 = np0[1];
            const f32x4* np1 = (const f32x4*)(ea + (size_t)(un * 32 + 16 + ln) * 8);
            nea10 = np1[0]; nea11 = np1[1];
        }

        // ---- h = relu(ea@W1 + b1) via MFMA (B-frag only kg==0 lanes nonzero)
        bf16x8 eb0, eb1;
        if (kg == 0) {
            eb0[0]=(__bf16)ea00[0]; eb0[1]=(__bf16)ea00[1]; eb0[2]=(__bf16)ea00[2]; eb0[3]=(__bf16)ea00[3];
            eb0[4]=(__bf16)ea01[0]; eb0[5]=(__bf16)ea01[1]; eb0[6]=(__bf16)ea01[2]; eb0[7]=(__bf16)ea01[3];
            eb1[0]=(__bf16)ea10[0]; eb1[1]=(__bf16)ea10[1]; eb1[2]=(__bf16)ea10[2]; eb1[3]=(__bf16)ea10[3];
            eb1[4]=(__bf16)ea11[0]; eb1[5]=(__bf16)ea11[1]; eb1[6]=(__bf16)ea11[2]; eb1[7]=(__bf16)ea11[3];
        } else {
            eb0[0]=zb; eb0[1]=zb; eb0[2]=zb; eb0[3]=zb; eb0[4]=zb; eb0[5]=zb; eb0[6]=zb; eb0[7]=zb;
            eb1 = eb0;
        }
        f32x4 hA0 = __builtin_amdgcn_mfma_f32_16x16x32_bf16(aw0, eb0, z4, 0, 0, 0);
        f32x4 hA1 = __builtin_amdgcn_mfma_f32_16x16x32_bf16(aw1, eb0, z4, 0, 0, 0);
        f32x4 hB0 = __builtin_amdgcn_mfma_f32_16x16x32_bf16(aw0, eb1, z4, 0, 0, 0);
        f32x4 hB1 = __builtin_amdgcn_mfma_f32_16x16x32_bf16(aw1, eb1, z4, 0, 0, 0);

        float h0[8], h1[8];
#pragma unroll
        for (int r = 0; r < 4; ++r) {
            const float blo = b1l[4 * kg + r], bhi = b1l[16 + 4 * kg + r];
            h0[r]     = fmaxf(hA0[r] + blo, 0.f);
            h0[4 + r] = fmaxf(hA1[r] + bhi, 0.f);
            h1[r]     = fmaxf(hB0[r] + blo, 0.f);
            h1[4 + r] = fmaxf(hB1[r] + bhi, 0.f);
        }

        float xr0[16], xr1[16];
        xr0[0]=xa0[0]; xr0[1]=xa0[1]; xr0[2]=xa0[2]; xr0[3]=xa0[3];
        xr0[4]=xa1[0]; xr0[5]=xa1[1]; xr0[6]=xa1[2]; xr0[7]=xa1[3];
        xr0[8]=xa2[0]; xr0[9]=xa2[1]; xr0[10]=xa2[2]; xr0[11]=xa2[3];
        xr0[12]=xa3[0]; xr0[13]=xa3[1]; xr0[14]=xa3[2]; xr0[15]=xa3[3];
        xr1[0]=xb0[0]; xr1[1]=xb0[1]; xr1[2]=xb0[2]; xr1[3]=xb0[3];
        xr1[4]=xb1[0]; xr1[5]=xb1[1]; xr1[6]=xb1[2]; xr1[7]=xb1[3];
        xr1[8]=xb2[0]; xr1[9]=xb2[1]; xr1[10]=xb2[2]; xr1[11]=xb2[3];
        xr1[12]=xb3[0]; xr1[13]=xb3[1]; xr1[14]=xb3[2]; xr1[15]=xb3[3];

        f32x4 acc00 = z4, acc01 = z4, acc10 = z4, acc11 = z4;

#pragma unroll
        for (int kt = 0; kt < 16; ++kt) {
            const bf16x8 bf0 = *(const bf16x8*)(&w2l[(kt * 2 + 0) * 512 + lane * 8]);
            const bf16x8 bf1 = *(const bf16x8*)(&w2l[(kt * 2 + 1) * 512 + lane * 8]);
            const float xv0 = xr0[kt], xv1 = xr1[kt];
            bf16x8 a0, a1;
#pragma unroll
            for (int j = 0; j < 8; ++j) {
                a0[j] = (__bf16)(xv0 * h0[j]);
                a1[j] = (__bf16)(xv1 * h1[j]);
            }
            acc00 = __builtin_amdgcn_mfma_f32_16x16x32_bf16(a0, bf0, acc00, 0, 0, 0);
            acc10 = __builtin_amdgcn_mfma_f32_16x16x32_bf16(a1, bf0, acc10, 0, 0, 0);
            acc01 = __builtin_amdgcn_mfma_f32_16x16x32_bf16(a0, bf1, acc01, 0, 0, 0);
            acc11 = __builtin_amdgcn_mfma_f32_16x16x32_bf16(a1, bf1, acc11, 0, 0, 0);
        }
        { // 17th K-tile folds b2
            const f32x4 xs0 = (kg == 0) ? xa0 : ((kg == 1) ? xa1 : ((kg == 2) ? xa2 : xa3));
            const f32x4 xs1 = (kg == 0) ? xb0 : ((kg == 1) ? xb1 : ((kg == 2) ? xb2 : xb3));
            bf16x8 a0, a1;
            a0[0]=(__bf16)xs0[0]; a0[1]=(__bf16)xs0[1]; a0[2]=(__bf16)xs0[2]; a0[3]=(__bf16)xs0[3];
            a0[4]=zb; a0[5]=zb; a0[6]=zb; a0[7]=zb;
            a1[0]=(__bf16)xs1[0]; a1[1]=(__bf16)xs1[1]; a1[2]=(__bf16)xs1[2]; a1[3]=(__bf16)xs1[3];
            a1[4]=zb; a1[5]=zb; a1[6]=zb; a1[7]=zb;
            const bf16x8 bf0 = *(const bf16x8*)(&w2l[(16 * 2 + 0) * 512 + lane * 8]);
            const bf16x8 bf1 = *(const bf16x8*)(&w2l[(16 * 2 + 1) * 512 + lane * 8]);
            acc00 = __builtin_amdgcn_mfma_f32_16x16x32_bf16(a0, bf0, acc00, 0, 0, 0);
            acc10 = __builtin_amdgcn_mfma_f32_16x16x32_bf16(a1, bf0, acc10, 0, 0, 0);
            acc01 = __builtin_amdgcn_mfma_f32_16x16x32_bf16(a0, bf1, acc01, 0, 0, 0);
            acc11 = __builtin_amdgcn_mfma_f32_16x16x32_bf16(a1, bf1, acc11, 0, 0, 0);
        }

        // ---- coalesced row-aligned scatter (16 lanes cover one dst row)
        atomicAdd(&agg[d0.x * 32 + ln],      acc00[0]);
        atomicAdd(&agg[d0.y * 32 + ln],      acc00[1]);
        atomicAdd(&agg[d0.z * 32 + ln],      acc00[2]);
        atomicAdd(&agg[d0.w * 32 + ln],      acc00[3]);
        atomicAdd(&agg[d0.x * 32 + 16 + ln], acc01[0]);
        atomicAdd(&agg[d0.y * 32 + 16 + ln], acc01[1]);
        atomicAdd(&agg[d0.z * 32 + 16 + ln], acc01[2]);
        atomicAdd(&agg[d0.w * 32 + 16 + ln], acc01[3]);
        atomicAdd(&agg[d1.x * 32 + ln],      acc10[0]);
        atomicAdd(&agg[d1.y * 32 + ln],      acc10[1]);
        atomicAdd(&agg[d1.z * 32 + ln],      acc10[2]);
        atomicAdd(&agg[d1.w * 32 + ln],      acc10[3]);
        atomicAdd(&agg[d1.x * 32 + 16 + ln], acc11[0]);
        atomicAdd(&agg[d1.y * 32 + 16 + ln], acc11[1]);
        atomicAdd(&agg[d1.z * 32 + 16 + ln], acc11[2]);
        atomicAdd(&agg[d1.w * 32 + 16 + ln], acc11[3]);

        if (!pf) break;
        u = un;
        s0 = ns0; s1 = ns1;
        ea00 = nea00; ea01 = nea01; ea10 = nea10; ea11 = nea11;
    }
}

// ---------------------------------------------------------------------------
// K_node: fused  a = relu(agg/deg + x@root + bias) then out = a@Wlin + blin
// deg = sum of the 8 sub-counters.
// ---------------------------------------------------------------------------
__global__ void __launch_bounds__(256) k_node(const float* __restrict__ agg,
                                              const uint* __restrict__ cnt8,
                                              const float* __restrict__ x,
                                              const float* __restrict__ root,
                                              const float* __restrict__ bias,
                                              const float* __restrict__ Wlin,
                                              const float* __restrict__ blin,
                                              float* __restrict__ out) {
    __shared__ float al[256];
    const int n0 = blockIdx.x * 8;
    const int t = threadIdx.x;
    const int n = n0 + (t >> 5), h = t & 31;
    float a = 0.0f;
    if (n < N_NODES) {
        const uint4 c0 = *(const uint4*)(cnt8 + (size_t)n * 8);
        const uint4 c1 = *(const uint4*)(cnt8 + (size_t)n * 8 + 4);
        const float c = (float)(c0.x + c0.y + c0.z + c0.w + c1.x + c1.y + c1.z + c1.w);
        float s = agg[n * 32 + h] / fmaxf(c, 1.0f) + bias[h];
        const f32x4* xp = (const f32x4*)(x + (size_t)n * 16);
        const f32x4 x0 = xp[0], x1 = xp[1], x2 = xp[2], x3 = xp[3];
        float xv[16];
        xv[0]=x0[0]; xv[1]=x0[1]; xv[2]=x0[2]; xv[3]=x0[3];
        xv[4]=x1[0]; xv[5]=x1[1]; xv[6]=x1[2]; xv[7]=x1[3];
        xv[8]=x2[0]; xv[9]=x2[1]; xv[10]=x2[2]; xv[11]=x2[3];
        xv[12]=x3[0]; xv[13]=x3[1]; xv[14]=x3[2]; xv[15]=x3[3];
#pragma unroll
        for (int i = 0; i < 16; ++i) s += xv[i] * root[i * 32 + h];
        a = fmaxf(s, 0.0f);
    }
    al[t] = a;
    __syncthreads();
    if (t < 128) {
        const int nj = n0 + (t >> 4), j = t & 15;
        if (nj < N_NODES) {
            float s = blin[j];
#pragma unroll
            for (int h2 = 0; h2 < 32; ++h2) s += al[(t >> 4) * 32 + h2] * Wlin[h2 * 16 + j];
            out[nj * 16 + j] = s;
        }
    }
}

// ---------------------------------------------------------------------------
extern "C" void kernel_launch(void* const* d_in, const int* in_sizes, int n_in,
                              void* d_out, int out_size, void* d_ws, size_t ws_size,
                              hipStream_t stream) {
    const float* x    = (const float*)d_in[0];
    const float* ea   = (const float*)d_in[1];
    const float* W1   = (const float*)d_in[2];
    const float* b1   = (const float*)d_in[3];
    const float* W2   = (const float*)d_in[4];
    const float* b2   = (const float*)d_in[5];
    const float* root = (const float*)d_in[6];
    const float* bias = (const float*)d_in[7];
    const float* Wlin = (const float*)d_in[8];
    const float* blin = (const float*)d_in[9];
    const int*   ei   = (const int*)d_in[10];
    float* out = (float*)d_out;

    char* ws = (char*)d_ws;
    float*  agg    = (float*)(ws + 0);           // 3,200,000
    uint*   cnt8   = (uint*)(ws + 3200000);      //   800,000
    ushort* packed = (ushort*)(ws + 4000000);    //    36,864

    k_pre<<<782, 256, 0, stream>>>(W2, b2, W1, packed, (uint*)ws);
    k_edge<<<HB2 + EBLK, 512, 0, stream>>>(ea, x, ei, packed, b1, agg, cnt8);
    k_node<<<3125, 256, 0, stream>>>(agg, cnt8, x, root, bias, Wlin, blin, out);
}

// Round 21
// 75.647 us; speedup vs baseline: 1.9382x; 1.9382x over previous
//
#include <hip/hip_runtime.h>
#include <cstdint>

#define E_EDGES 400000
#define N_NODES 25000
#define NU      12500          // units of 32 edges (2 MFMA groups of 16)
#define NPACK   18432          // ushorts: 17 K-tiles (17408) + 2 W1^T A-frags (1024)
#define HBLOCKS 391            // histogram blocks (1024 edges each), co-scheduled
#define EBLK    1563           // edge-compute blocks
#define NWAVES  (EBLK*4)       // 6252 waves; each does <=2 units (unrolled)

typedef float  f32x4  __attribute__((ext_vector_type(4)));
typedef __bf16 bf16x8 __attribute__((ext_vector_type(8)));

static __device__ __forceinline__ ushort f2bf(float f) {
    union { __bf16 b; ushort u; } c; c.b = (__bf16)f; return c.u;
}

// ---------------------------------------------------------------------------
// K_pre: zero agg+cnt8 (grid-stride) AND pack W2(+b2)/W1^T frags. One dispatch.
// kap(kg,j) = j<4 ? 4kg+j : 16+4kg+(j-4)   (matches h-MFMA C layout)
// ---------------------------------------------------------------------------
__global__ void __launch_bounds__(256) k_pre(const float* __restrict__ W2,
                                             const float* __restrict__ b2,
                                             const float* __restrict__ W1,
                                             ushort* __restrict__ packed,
                                             uint* __restrict__ zbase) {
    const int t = blockIdx.x * 256 + threadIdx.x;
    // zero 1,000,000 uints: agg (800,000) + cnt8 (200,000)
    for (int i = t; i < 1000000; i += EBLK * 256) zbase[i] = 0u;
    if (t >= NPACK) return;
    float v = 0.0f;
    if (t < 17408) {
        int j  = t & 7;
        int ln = (t >> 3) & 15;
        int kg = (t >> 7) & 3;
        int nt = (t >> 9) & 1;
        int kt = t >> 10;
        int kap = (j < 4) ? (kg * 4 + j) : (16 + kg * 4 + (j - 4));
        if (kt < 16)       v = W2[kap * 512 + kt * 32 + nt * 16 + ln];
        else if (kap < 16) v = b2[kap * 32 + nt * 16 + ln];
    } else {
        int idx  = t - 17408;
        int half = idx >> 9;
        int lane = (idx >> 3) & 63;
        int j    = idx & 7;
        int kg = lane >> 4, ln = lane & 15;
        if (kg == 0) v = W1[j * 32 + half * 16 + ln];  // A[m=ln(+16*half)][k=j]
    }
    packed[t] = f2bf(v);
}

// ---------------------------------------------------------------------------
// K_edge: blocks < HBLOCKS: 8-way-spread dst histogram (cnt8[n][8], slot=e&7)
// — co-scheduled so the contended RMWs overlap edge compute.
// Blocks >= HBLOCKS: r4's proven body VERBATIM (72 VGPR / 55.3us): per wave
// exactly 2 units (32 edges each), fully unrolled (no loop-carried prefetch
// state); while computing unit u, prefetch unit u+NWAVES's indices + ea;
// x-gather for u issues first (its src idx prefetched last iteration).
// ---------------------------------------------------------------------------
__global__ void __launch_bounds__(256) k_edge(const float* __restrict__ ea,
                                              const float* __restrict__ x,
                                              const int* __restrict__ ei,
                                              const ushort* __restrict__ packed,
                                              const float* __restrict__ b1,
                                              float* __restrict__ agg,
                                              uint* __restrict__ cnt8) {
    if (blockIdx.x < HBLOCKS) {
        const int base = blockIdx.x * 1024 + threadIdx.x * 4;
        if (base < E_EDGES) {
            const int4 dv = *(const int4*)(ei + E_EDGES + base);
            atomicAdd(&cnt8[dv.x * 8 + ((base + 0) & 7)], 1u);
            atomicAdd(&cnt8[dv.y * 8 + ((base + 1) & 7)], 1u);
            atomicAdd(&cnt8[dv.z * 8 + ((base + 2) & 7)], 1u);
            atomicAdd(&cnt8[dv.w * 8 + ((base + 3) & 7)], 1u);
        }
        return;
    }

    __shared__ alignas(16) ushort w2l[NPACK];
    __shared__ float b1l[32];
    {
        const uint4* s = (const uint4*)packed;
        uint4* d = (uint4*)w2l;
        for (int i = threadIdx.x; i < NPACK / 8; i += 256) d[i] = s[i];
        if (threadIdx.x < 32) b1l[threadIdx.x] = b1[threadIdx.x];
    }
    __syncthreads();

    const int lane = threadIdx.x & 63;
    const int ln = lane & 15;
    const int kg = lane >> 4;
    const int wid = (blockIdx.x - HBLOCKS) * 4 + (threadIdx.x >> 6);

    // loop-invariant A-frags for the h-MFMA (W1^T)
    const bf16x8 aw0 = *(const bf16x8*)(&w2l[17408 + lane * 8]);
    const bf16x8 aw1 = *(const bf16x8*)(&w2l[17408 + 512 + lane * 8]);
    const f32x4 z4 = {0.f, 0.f, 0.f, 0.f};
    const __bf16 zb = (__bf16)0.0f;

    int u = wid;                    // wid < 6252 <= NU always valid
    // ---- prologue: indices + ea for unit u
    int s0 = ei[u * 32 + ln];
    int s1 = ei[u * 32 + 16 + ln];
    int4 d0 = *(const int4*)(ei + E_EDGES + u * 32 + kg * 4);
    int4 d1 = *(const int4*)(ei + E_EDGES + u * 32 + 16 + kg * 4);
    const f32x4* ep0 = (const f32x4*)(ea + (size_t)(u * 32 + ln) * 8);
    f32x4 ea00 = ep0[0], ea01 = ep0[1];
    const f32x4* ep1 = (const f32x4*)(ea + (size_t)(u * 32 + 16 + ln) * 8);
    f32x4 ea10 = ep1[0], ea11 = ep1[1];

#pragma unroll
    for (int it = 0; it < 2; ++it) {
        const int un = u + NWAVES;
        const bool pf = (it == 0) && (un < NU);

        // ---- x gathers for current unit (s0/s1 already in flight)
        const f32x4* xp0 = (const f32x4*)(x + (size_t)s0 * 16);
        const f32x4 xa0 = xp0[0], xa1 = xp0[1], xa2 = xp0[2], xa3 = xp0[3];
        const f32x4* xp1 = (const f32x4*)(x + (size_t)s1 * 16);
        const f32x4 xb0 = xp1[0], xb1 = xp1[1], xb2 = xp1[2], xb3 = xp1[3];

        // ---- prefetch next unit's indices + ea (latency hidden under MFMAs)
        int ns0 = 0, ns1 = 0;
        int4 nd0 = {0,0,0,0}, nd1 = {0,0,0,0};
        f32x4 nea00 = z4, nea01 = z4, nea10 = z4, nea11 = z4;
        if (pf) {
            ns0 = ei[un * 32 + ln];
            ns1 = ei[un * 32 + 16 + ln];
            nd0 = *(const int4*)(ei + E_EDGES + un * 32 + kg * 4);
            nd1 = *(const int4*)(ei + E_EDGES + un * 32 + 16 + kg * 4);
            const f32x4* np0 = (const f32x4*)(ea + (size_t)(un * 32 + ln) * 8);
            nea00 = np0[0]; nea01 = np0[1];
            const f32x4* np1 = (const f32x4*)(ea + (size_t)(un * 32 + 16 + ln) * 8);
            nea10 = np1[0]; nea11 = np1[1];
        }

        // ---- h = relu(ea@W1 + b1) via MFMA (B-frag only kg==0 lanes nonzero)
        bf16x8 eb0, eb1;
        if (kg == 0) {
            eb0[0]=(__bf16)ea00[0]; eb0[1]=(__bf16)ea00[1]; eb0[2]=(__bf16)ea00[2]; eb0[3]=(__bf16)ea00[3];
            eb0[4]=(__bf16)ea01[0]; eb0[5]=(__bf16)ea01[1]; eb0[6]=(__bf16)ea01[2]; eb0[7]=(__bf16)ea01[3];
            eb1[0]=(__bf16)ea10[0]; eb1[1]=(__bf16)ea10[1]; eb1[2]=(__bf16)ea10[2]; eb1[3]=(__bf16)ea10[3];
            eb1[4]=(__bf16)ea11[0]; eb1[5]=(__bf16)ea11[1]; eb1[6]=(__bf16)ea11[2]; eb1[7]=(__bf16)ea11[3];
        } else {
            eb0[0]=zb; eb0[1]=zb; eb0[2]=zb; eb0[3]=zb; eb0[4]=zb; eb0[5]=zb; eb0[6]=zb; eb0[7]=zb;
            eb1 = eb0;
        }
        f32x4 hA0 = __builtin_amdgcn_mfma_f32_16x16x32_bf16(aw0, eb0, z4, 0, 0, 0);
        f32x4 hA1 = __builtin_amdgcn_mfma_f32_16x16x32_bf16(aw1, eb0, z4, 0, 0, 0);
        f32x4 hB0 = __builtin_amdgcn_mfma_f32_16x16x32_bf16(aw0, eb1, z4, 0, 0, 0);
        f32x4 hB1 = __builtin_amdgcn_mfma_f32_16x16x32_bf16(aw1, eb1, z4, 0, 0, 0);

        float h0[8], h1[8];
#pragma unroll
        for (int r = 0; r < 4; ++r) {
            const float blo = b1l[4 * kg + r], bhi = b1l[16 + 4 * kg + r];
            h0[r]     = fmaxf(hA0[r] + blo, 0.f);
            h0[4 + r] = fmaxf(hA1[r] + bhi, 0.f);
            h1[r]     = fmaxf(hB0[r] + blo, 0.f);
            h1[4 + r] = fmaxf(hB1[r] + bhi, 0.f);
        }

        float xr0[16], xr1[16];
        xr0[0]=xa0[0]; xr0[1]=xa0[1]; xr0[2]=xa0[2]; xr0[3]=xa0[3];
        xr0[4]=xa1[0]; xr0[5]=xa1[1]; xr0[6]=xa1[2]; xr0[7]=xa1[3];
        xr0[8]=xa2[0]; xr0[9]=xa2[1]; xr0[10]=xa2[2]; xr0[11]=xa2[3];
        xr0[12]=xa3[0]; xr0[13]=xa3[1]; xr0[14]=xa3[2]; xr0[15]=xa3[3];
        xr1[0]=xb0[0]; xr1[1]=xb0[1]; xr1[2]=xb0[2]; xr1[3]=xb0[3];
        xr1[4]=xb1[0]; xr1[5]=xb1[1]; xr1[6]=xb1[2]; xr1[7]=xb1[3];
        xr1[8]=xb2[0]; xr1[9]=xb2[1]; xr1[10]=xb2[2]; xr1[11]=xb2[3];
        xr1[12]=xb3[0]; xr1[13]=xb3[1]; xr1[14]=xb3[2]; xr1[15]=xb3[3];

        f32x4 acc00 = z4, acc01 = z4, acc10 = z4, acc11 = z4;

#pragma unroll
        for (int kt = 0; kt < 16; ++kt) {
            const bf16x8 bf0 = *(const bf16x8*)(&w2l[(kt * 2 + 0) * 512 + lane * 8]);
            const bf16x8 bf1 = *(const bf16x8*)(&w2l[(kt * 2 + 1) * 512 + lane * 8]);
            const float xv0 = xr0[kt], xv1 = xr1[kt];
            bf16x8 a0, a1;
#pragma unroll
            for (int j = 0; j < 8; ++j) {
                a0[j] = (__bf16)(xv0 * h0[j]);
                a1[j] = (__bf16)(xv1 * h1[j]);
            }
            acc00 = __builtin_amdgcn_mfma_f32_16x16x32_bf16(a0, bf0, acc00, 0, 0, 0);
            acc10 = __builtin_amdgcn_mfma_f32_16x16x32_bf16(a1, bf0, acc10, 0, 0, 0);
            acc01 = __builtin_amdgcn_mfma_f32_16x16x32_bf16(a0, bf1, acc01, 0, 0, 0);
            acc11 = __builtin_amdgcn_mfma_f32_16x16x32_bf16(a1, bf1, acc11, 0, 0, 0);
        }
        { // 17th K-tile folds b2
            const f32x4 xs0 = (kg == 0) ? xa0 : ((kg == 1) ? xa1 : ((kg == 2) ? xa2 : xa3));
            const f32x4 xs1 = (kg == 0) ? xb0 : ((kg == 1) ? xb1 : ((kg == 2) ? xb2 : xb3));
            bf16x8 a0, a1;
            a0[0]=(__bf16)xs0[0]; a0[1]=(__bf16)xs0[1]; a0[2]=(__bf16)xs0[2]; a0[3]=(__bf16)xs0[3];
            a0[4]=zb; a0[5]=zb; a0[6]=zb; a0[7]=zb;
            a1[0]=(__bf16)xs1[0]; a1[1]=(__bf16)xs1[1]; a1[2]=(__bf16)xs1[2]; a1[3]=(__bf16)xs1[3];
            a1[4]=zb; a1[5]=zb; a1[6]=zb; a1[7]=zb;
            const bf16x8 bf0 = *(const bf16x8*)(&w2l[(16 * 2 + 0) * 512 + lane * 8]);
            const bf16x8 bf1 = *(const bf16x8*)(&w2l[(16 * 2 + 1) * 512 + lane * 8]);
            acc00 = __builtin_amdgcn_mfma_f32_16x16x32_bf16(a0, bf0, acc00, 0, 0, 0);
            acc10 = __builtin_amdgcn_mfma_f32_16x16x32_bf16(a1, bf0, acc10, 0, 0, 0);
            acc01 = __builtin_amdgcn_mfma_f32_16x16x32_bf16(a0, bf1, acc01, 0, 0, 0);
            acc11 = __builtin_amdgcn_mfma_f32_16x16x32_bf16(a1, bf1, acc11, 0, 0, 0);
        }

        // ---- coalesced row-aligned scatter (16 lanes cover one dst row)
        atomicAdd(&agg[d0.x * 32 + ln],      acc00[0]);
        atomicAdd(&agg[d0.y * 32 + ln],      acc00[1]);
        atomicAdd(&agg[d0.z * 32 + ln],      acc00[2]);
        atomicAdd(&agg[d0.w * 32 + ln],      acc00[3]);
        atomicAdd(&agg[d0.x * 32 + 16 + ln], acc01[0]);
        atomicAdd(&agg[d0.y * 32 + 16 + ln], acc01[1]);
        atomicAdd(&agg[d0.z * 32 + 16 + ln], acc01[2]);
        atomicAdd(&agg[d0.w * 32 + 16 + ln], acc01[3]);
        atomicAdd(&agg[d1.x * 32 + ln],      acc10[0]);
        atomicAdd(&agg[d1.y * 32 + ln],      acc10[1]);
        atomicAdd(&agg[d1.z * 32 + ln],      acc10[2]);
        atomicAdd(&agg[d1.w * 32 + ln],      acc10[3]);
        atomicAdd(&agg[d1.x * 32 + 16 + ln], acc11[0]);
        atomicAdd(&agg[d1.y * 32 + 16 + ln], acc11[1]);
        atomicAdd(&agg[d1.z * 32 + 16 + ln], acc11[2]);
        atomicAdd(&agg[d1.w * 32 + 16 + ln], acc11[3]);

        if (!pf) break;
        u = un;
        s0 = ns0; s1 = ns1; d0 = nd0; d1 = nd1;
        ea00 = nea00; ea01 = nea01; ea10 = nea10; ea11 = nea11;
    }
}

// ---------------------------------------------------------------------------
// K_node: fused  a = relu(agg/deg + x@root + bias) then out = a@Wlin + blin
// deg = sum of the 8 sub-counters.
// ---------------------------------------------------------------------------
__global__ void __launch_bounds__(256) k_node(const float* __restrict__ agg,
                                              const uint* __restrict__ cnt8,
                                              const float* __restrict__ x,
                                              const float* __restrict__ root,
                                              const float* __restrict__ bias,
                                              const float* __restrict__ Wlin,
                                              const float* __restrict__ blin,
                                              float* __restrict__ out) {
    __shared__ float al[256];
    const int n0 = blockIdx.x * 8;
    const int t = threadIdx.x;
    const int n = n0 + (t >> 5), h = t & 31;
    float a = 0.0f;
    if (n < N_NODES) {
        const uint4 c0 = *(const uint4*)(cnt8 + (size_t)n * 8);
        const uint4 c1 = *(const uint4*)(cnt8 + (size_t)n * 8 + 4);
        const float c = (float)(c0.x + c0.y + c0.z + c0.w + c1.x + c1.y + c1.z + c1.w);
        float s = agg[n * 32 + h] / fmaxf(c, 1.0f) + bias[h];
        const f32x4* xp = (const f32x4*)(x + (size_t)n * 16);
        const f32x4 x0 = xp[0], x1 = xp[1], x2 = xp[2], x3 = xp[3];
        float xv[16];
        xv[0]=x0[0]; xv[1]=x0[1]; xv[2]=x0[2]; xv[3]=x0[3];
        xv[4]=x1[0]; xv[5]=x1[1]; xv[6]=x1[2]; xv[7]=x1[3];
        xv[8]=x2[0]; xv[9]=x2[1]; xv[10]=x2[2]; xv[11]=x2[3];
        xv[12]=x3[0]; xv[13]=x3[1]; xv[14]=x3[2]; xv[15]=x3[3];
#pragma unroll
        for (int i = 0; i < 16; ++i) s += xv[i] * root[i * 32 + h];
        a = fmaxf(s, 0.0f);
    }
    al[t] = a;
    __syncthreads();
    if (t < 128) {
        const int nj = n0 + (t >> 4), j = t & 15;
        if (nj < N_NODES) {
            float s = blin[j];
#pragma unroll
            for (int h2 = 0; h2 < 32; ++h2) s += al[(t >> 4) * 32 + h2] * Wlin[h2 * 16 + j];
            out[nj * 16 + j] = s;
        }
    }
}

// ---------------------------------------------------------------------------
extern "C" void kernel_launch(void* const* d_in, const int* in_sizes, int n_in,
                              void* d_out, int out_size, void* d_ws, size_t ws_size,
                              hipStream_t stream) {
    const float* x    = (const float*)d_in[0];
    const float* ea   = (const float*)d_in[1];
    const float* W1   = (const float*)d_in[2];
    const float* b1   = (const float*)d_in[3];
    const float* W2   = (const float*)d_in[4];
    const float* b2   = (const float*)d_in[5];
    const float* root = (const float*)d_in[6];
    const float* bias = (const float*)d_in[7];
    const float* Wlin = (const float*)d_in[8];
    const float* blin = (const float*)d_in[9];
    const int*   ei   = (const int*)d_in[10];
    float* out = (float*)d_out;

    char* ws = (char*)d_ws;
    float*  agg    = (float*)(ws + 0);           // 3,200,000
    uint*   cnt8   = (uint*)(ws + 3200000);      //   800,000
    ushort* packed = (ushort*)(ws + 4000000);    //    36,864

    k_pre<<<EBLK, 256, 0, stream>>>(W2, b2, W1, packed, (uint*)ws);
    k_edge<<<HBLOCKS + EBLK, 256, 0, stream>>>(ea, x, ei, packed, b1, agg, cnt8);
    k_node<<<3125, 256, 0, stream>>>(agg, cnt8, x, root, bias, Wlin, blin, out);
}